// Round 1
// baseline (551.728 us; speedup 1.0000x reference)
//
#include <hip/hip_runtime.h>
#include <hip/hip_bf16.h>

#define D_DIM 256
#define H_DIM 128
#define R_DIM 4

// ---------------- K_v: v1[r][d] = sum_h W[r][d][h]*a1[h]; v2 with a2; c1[r]=b[r].a1, c2[r]=b[r].a2
__global__ void kv_kernel(const float* __restrict__ W, const float* __restrict__ b,
                          const float* __restrict__ a,
                          float* __restrict__ v1, float* __restrict__ v2,
                          float* __restrict__ c1, float* __restrict__ c2) {
    int t = blockIdx.x * blockDim.x + threadIdx.x;
    if (t < R_DIM * D_DIM) {
        int r = t >> 8;          // /256
        int d = t & 255;
        const float* wp = W + ((size_t)r * D_DIM + d) * H_DIM;
        float acc1 = 0.f, acc2 = 0.f;
        for (int h = 0; h < H_DIM; ++h) {
            float w = wp[h];
            acc1 += w * a[h];
            acc2 += w * a[H_DIM + h];
        }
        v1[t] = acc1; v2[t] = acc2;
    }
    if (t < R_DIM) {
        const float* bp = b + t * H_DIM;
        float acc1 = 0.f, acc2 = 0.f;
        for (int h = 0; h < H_DIM; ++h) {
            acc1 += bp[h] * a[h];
            acc2 += bp[h] * a[H_DIM + h];
        }
        c1[t] = acc1; c2[t] = acc2;
    }
}

// ---------------- K_s: s1[r*N+n] = x[n].v1[r] + c1[r]; s2 likewise
__global__ void ks_kernel(const float* __restrict__ x,
                          const float* __restrict__ v1, const float* __restrict__ v2,
                          const float* __restrict__ c1, const float* __restrict__ c2,
                          float* __restrict__ s1, float* __restrict__ s2, int N) {
    __shared__ float sv1[R_DIM * D_DIM];
    __shared__ float sv2[R_DIM * D_DIM];
    for (int i = threadIdx.x; i < R_DIM * D_DIM; i += blockDim.x) {
        sv1[i] = v1[i]; sv2[i] = v2[i];
    }
    __syncthreads();
    int n = blockIdx.x * blockDim.x + threadIdx.x;
    if (n >= N) return;
    float a1[R_DIM] = {0.f, 0.f, 0.f, 0.f};
    float a2[R_DIM] = {0.f, 0.f, 0.f, 0.f};
    const float4* xp = (const float4*)(x + (size_t)n * D_DIM);
    for (int d4 = 0; d4 < D_DIM / 4; ++d4) {
        float4 xv = xp[d4];
        #pragma unroll
        for (int r = 0; r < R_DIM; ++r) {
            float4 w1 = *(const float4*)&sv1[r * D_DIM + d4 * 4];
            float4 w2 = *(const float4*)&sv2[r * D_DIM + d4 * 4];
            a1[r] += xv.x * w1.x + xv.y * w1.y + xv.z * w1.z + xv.w * w1.w;
            a2[r] += xv.x * w2.x + xv.y * w2.y + xv.z * w2.z + xv.w * w2.w;
        }
    }
    #pragma unroll
    for (int r = 0; r < R_DIM; ++r) {
        s1[(size_t)r * N + n] = a1[r] + c1[r];
        s2[(size_t)r * N + n] = a2[r] + c2[r];
    }
}

// ---------------- GEMM: Hout[r][n][h] = bf16( x[n] . W[r][:,h] + b[r][h] )
// fp32 tiled 64x64, 256 threads, 4x4 per thread, BK=16.
__global__ void gemm_kernel(const float* __restrict__ x, const float* __restrict__ W,
                            const float* __restrict__ b, __hip_bfloat16* __restrict__ Hout,
                            int N) {
    __shared__ float As[16][64];   // [k][m]
    __shared__ float Bs[16][64];   // [k][c]
    const int t = threadIdx.x;
    const int ty = t >> 4, tx = t & 15;
    const int row0 = blockIdx.y * 64;
    const int col0 = blockIdx.x * 64;        // global col in [0, 512)
    const int r = col0 >> 7;                 // relation
    const int h0 = col0 & 127;               // 0 or 64
    float acc[4][4] = {};
    for (int k0 = 0; k0 < D_DIM; k0 += 16) {
        { // load A tile 64x16 via float4
            int lr = t >> 2;
            int lk = (t & 3) * 4;
            int gr = row0 + lr;
            float4 v = make_float4(0.f, 0.f, 0.f, 0.f);
            if (gr < N) v = *(const float4*)(x + (size_t)gr * D_DIM + k0 + lk);
            As[lk + 0][lr] = v.x; As[lk + 1][lr] = v.y;
            As[lk + 2][lr] = v.z; As[lk + 3][lr] = v.w;
        }
        { // load B tile 16x64 via float4
            int lk = t >> 4;
            int lc = (t & 15) * 4;
            const float* wp = W + ((size_t)r * D_DIM + (k0 + lk)) * H_DIM + h0 + lc;
            *(float4*)&Bs[lk][lc] = *(const float4*)wp;
        }
        __syncthreads();
        #pragma unroll
        for (int kk = 0; kk < 16; ++kk) {
            float4 a4 = *(const float4*)&As[kk][ty * 4];
            float4 b4 = *(const float4*)&Bs[kk][tx * 4];
            acc[0][0] += a4.x * b4.x; acc[0][1] += a4.x * b4.y; acc[0][2] += a4.x * b4.z; acc[0][3] += a4.x * b4.w;
            acc[1][0] += a4.y * b4.x; acc[1][1] += a4.y * b4.y; acc[1][2] += a4.y * b4.z; acc[1][3] += a4.y * b4.w;
            acc[2][0] += a4.z * b4.x; acc[2][1] += a4.z * b4.y; acc[2][2] += a4.z * b4.z; acc[2][3] += a4.z * b4.w;
            acc[3][0] += a4.w * b4.x; acc[3][1] += a4.w * b4.y; acc[3][2] += a4.w * b4.z; acc[3][3] += a4.w * b4.w;
        }
        __syncthreads();
    }
    #pragma unroll
    for (int i = 0; i < 4; ++i) {
        int gr = row0 + ty * 4 + i;
        if (gr >= N) continue;
        size_t base = ((size_t)r * N + gr) * H_DIM + h0 + tx * 4;
        #pragma unroll
        for (int j = 0; j < 4; ++j) {
            float val = acc[i][j] + b[r * H_DIM + h0 + tx * 4 + j];
            Hout[base + j] = __float2bfloat16(val);
        }
    }
}

// ---------------- per-edge scores + per-row slot assignment
__global__ void kscore_kernel(const int* __restrict__ eidx, const int* __restrict__ etype,
                              const float* __restrict__ s1, const float* __restrict__ s2,
                              float* __restrict__ escore, int* __restrict__ slot,
                              int* __restrict__ cnt, int N, int E) {
    int e = blockIdx.x * blockDim.x + threadIdx.x;
    if (e >= E) return;
    int row = eidx[e];
    int col = eidx[E + e];
    int r = etype[e];
    float sc = s1[(size_t)r * N + row] + s2[(size_t)r * N + col];
    sc = (sc >= 0.f) ? sc : 0.2f * sc;
    escore[e] = sc;
    slot[e] = atomicAdd(&cnt[row], 1);
}

// ---------------- segment allocation (unordered, contiguous per row)
__global__ void kalloc_kernel(const int* __restrict__ cnt, int* __restrict__ ofs,
                              int* __restrict__ counter, int N) {
    int n = blockIdx.x * blockDim.x + threadIdx.x;
    if (n < N) ofs[n] = atomicAdd(counter, cnt[n]);
}

// ---------------- place edges into row-grouped list
__global__ void kplace_kernel(const int* __restrict__ eidx, const int* __restrict__ ofs,
                              const int* __restrict__ slot, int* __restrict__ perm, int E) {
    int e = blockIdx.x * blockDim.x + threadIdx.x;
    if (e < E) {
        int row = eidx[e];
        perm[ofs[row] + slot[e]] = e;
    }
}

// ---------------- one wave per destination row: softmax per relation + weighted gather
__global__ void __launch_bounds__(64)
krow_kernel(const int* __restrict__ perm, const int* __restrict__ eidx,
            const int* __restrict__ etype, const float* __restrict__ escore,
            const int* __restrict__ ofs, const int* __restrict__ cnt,
            const __hip_bfloat16* __restrict__ Hall,
            float* __restrict__ out, int N, int E) {
    int n = blockIdx.x;
    int lane = threadIdx.x;  // 64
    int start = ofs[n];
    int deg = cnt[n];

    // pass 1: per-relation max
    float m[R_DIM] = {-1e30f, -1e30f, -1e30f, -1e30f};
    for (int i = lane; i < deg; i += 64) {
        int e = perm[start + i];
        int r = etype[e];
        m[r] = fmaxf(m[r], escore[e]);
    }
    #pragma unroll
    for (int r = 0; r < R_DIM; ++r)
        #pragma unroll
        for (int o = 32; o > 0; o >>= 1)
            m[r] = fmaxf(m[r], __shfl_xor(m[r], o));

    // pass 2: per-relation sum
    float s[R_DIM] = {0.f, 0.f, 0.f, 0.f};
    for (int i = lane; i < deg; i += 64) {
        int e = perm[start + i];
        int r = etype[e];
        s[r] += __expf(escore[e] - m[r]);
    }
    #pragma unroll
    for (int r = 0; r < R_DIM; ++r)
        #pragma unroll
        for (int o = 32; o > 0; o >>= 1)
            s[r] += __shfl_xor(s[r], o);

    float inv[R_DIM];
    #pragma unroll
    for (int r = 0; r < R_DIM; ++r) inv[r] = (s[r] > 0.f) ? 1.f / s[r] : 1.f;

    // pass 3: weighted accumulate, lanes parallel over H
    float acc0 = 0.f, acc1 = 0.f;
    for (int i = 0; i < deg; ++i) {
        int e = perm[start + i];
        int r = etype[e];
        int col = eidx[E + e];
        float alpha = __expf(escore[e] - m[r]) * inv[r];
        const __hip_bfloat16* hp = Hall + ((size_t)r * N + col) * H_DIM;
        acc0 += alpha * __bfloat162float(hp[lane]);
        acc1 += alpha * __bfloat162float(hp[lane + 64]);
    }
    out[(size_t)n * H_DIM + lane] = acc0;
    out[(size_t)n * H_DIM + 64 + lane] = acc1;
}

// ---------------- launch
static inline char* carve(char*& p, size_t bytes) {
    char* q = p;
    p += (bytes + 255) & ~(size_t)255;
    return q;
}

extern "C" void kernel_launch(void* const* d_in, const int* in_sizes, int n_in,
                              void* d_out, int out_size, void* d_ws, size_t ws_size,
                              hipStream_t stream) {
    const float* x     = (const float*)d_in[0];
    const int*   eidx  = (const int*)d_in[1];
    const int*   etype = (const int*)d_in[2];
    const float* a     = (const float*)d_in[3];
    const float* W     = (const float*)d_in[4];
    const float* b     = (const float*)d_in[5];
    float* out = (float*)d_out;

    const int E = in_sizes[2];
    const int N = in_sizes[0] / D_DIM;

    char* p = (char*)d_ws;
    __hip_bfloat16* Hall = (__hip_bfloat16*)carve(p, (size_t)R_DIM * N * H_DIM * 2);
    float* s1     = (float*)carve(p, (size_t)R_DIM * N * 4);
    float* s2     = (float*)carve(p, (size_t)R_DIM * N * 4);
    float* v1     = (float*)carve(p, R_DIM * D_DIM * 4);
    float* v2     = (float*)carve(p, R_DIM * D_DIM * 4);
    float* c1     = (float*)carve(p, 64);
    float* c2     = (float*)carve(p, 64);
    float* escore = (float*)carve(p, (size_t)E * 4);
    int*   slot   = (int*)carve(p, (size_t)E * 4);
    int*   perm   = (int*)carve(p, (size_t)E * 4);
    int*   ofs    = (int*)carve(p, (size_t)N * 4);
    int*   cnt    = (int*)carve(p, (size_t)N * 4 + 4);   // counter lives at cnt[N]
    int*   counter = cnt + N;

    // zero cnt + counter (contiguous)
    hipMemsetAsync(cnt, 0, (size_t)N * 4 + 4, stream);

    kv_kernel<<<4, 256, 0, stream>>>(W, b, a, v1, v2, c1, c2);
    ks_kernel<<<(N + 255) / 256, 256, 0, stream>>>(x, v1, v2, c1, c2, s1, s2, N);
    gemm_kernel<<<dim3(8, (N + 63) / 64), 256, 0, stream>>>(x, W, b, Hall, N);
    kscore_kernel<<<(E + 255) / 256, 256, 0, stream>>>(eidx, etype, s1, s2, escore, slot, cnt, N, E);
    kalloc_kernel<<<(N + 255) / 256, 256, 0, stream>>>(cnt, ofs, counter, N);
    kplace_kernel<<<(E + 255) / 256, 256, 0, stream>>>(eidx, ofs, slot, perm, E);
    krow_kernel<<<N, 64, 0, stream>>>(perm, eidx, etype, escore, ofs, cnt, Hall, out, N, E);
}

// Round 2
// 337.668 us; speedup vs baseline: 1.6339x; 1.6339x over previous
//
#include <hip/hip_runtime.h>
#include <hip/hip_bf16.h>

#define D_DIM 256
#define H_DIM 128
#define R_DIM 4

// ---------------- K_v: v1[r][d] = sum_h W[r][d][h]*a1[h]; v2 with a2; c1[r]=b[r].a1, c2[r]=b[r].a2
__global__ void kv_kernel(const float* __restrict__ W, const float* __restrict__ b,
                          const float* __restrict__ a,
                          float* __restrict__ v1, float* __restrict__ v2,
                          float* __restrict__ c1, float* __restrict__ c2) {
    int t = blockIdx.x * blockDim.x + threadIdx.x;
    if (t < R_DIM * D_DIM) {
        int r = t >> 8;          // /256
        int d = t & 255;
        const float* wp = W + ((size_t)r * D_DIM + d) * H_DIM;
        float acc1 = 0.f, acc2 = 0.f;
        for (int h = 0; h < H_DIM; ++h) {
            float w = wp[h];
            acc1 += w * a[h];
            acc2 += w * a[H_DIM + h];
        }
        v1[t] = acc1; v2[t] = acc2;
    }
    if (t < R_DIM) {
        const float* bp = b + t * H_DIM;
        float acc1 = 0.f, acc2 = 0.f;
        for (int h = 0; h < H_DIM; ++h) {
            acc1 += bp[h] * a[h];
            acc2 += bp[h] * a[H_DIM + h];
        }
        c1[t] = acc1; c2[t] = acc2;
    }
}

// ---------------- K_s: s1[r*N+n] = x[n].v1[r] + c1[r]; s2 likewise
__global__ void ks_kernel(const float* __restrict__ x,
                          const float* __restrict__ v1, const float* __restrict__ v2,
                          const float* __restrict__ c1, const float* __restrict__ c2,
                          float* __restrict__ s1, float* __restrict__ s2, int N) {
    __shared__ float sv1[R_DIM * D_DIM];
    __shared__ float sv2[R_DIM * D_DIM];
    for (int i = threadIdx.x; i < R_DIM * D_DIM; i += blockDim.x) {
        sv1[i] = v1[i]; sv2[i] = v2[i];
    }
    __syncthreads();
    int n = blockIdx.x * blockDim.x + threadIdx.x;
    if (n >= N) return;
    float a1[R_DIM] = {0.f, 0.f, 0.f, 0.f};
    float a2[R_DIM] = {0.f, 0.f, 0.f, 0.f};
    const float4* xp = (const float4*)(x + (size_t)n * D_DIM);
    for (int d4 = 0; d4 < D_DIM / 4; ++d4) {
        float4 xv = xp[d4];
        #pragma unroll
        for (int r = 0; r < R_DIM; ++r) {
            float4 w1 = *(const float4*)&sv1[r * D_DIM + d4 * 4];
            float4 w2 = *(const float4*)&sv2[r * D_DIM + d4 * 4];
            a1[r] += xv.x * w1.x + xv.y * w1.y + xv.z * w1.z + xv.w * w1.w;
            a2[r] += xv.x * w2.x + xv.y * w2.y + xv.z * w2.z + xv.w * w2.w;
        }
    }
    #pragma unroll
    for (int r = 0; r < R_DIM; ++r) {
        s1[(size_t)r * N + n] = a1[r] + c1[r];
        s2[(size_t)r * N + n] = a2[r] + c2[r];
    }
}

// ---------------- GEMM: Hout[r][n][h] = bf16( x[n] . W[r][:,h] + b[r][h] )
// fp32 tiled 64x64, 256 threads, 4x4 per thread, BK=16.
__global__ void gemm_kernel(const float* __restrict__ x, const float* __restrict__ W,
                            const float* __restrict__ b, __hip_bfloat16* __restrict__ Hout,
                            int N) {
    __shared__ float As[16][64];   // [k][m]
    __shared__ float Bs[16][64];   // [k][c]
    const int t = threadIdx.x;
    const int ty = t >> 4, tx = t & 15;
    const int row0 = blockIdx.y * 64;
    const int col0 = blockIdx.x * 64;        // global col in [0, 512)
    const int r = col0 >> 7;                 // relation
    const int h0 = col0 & 127;               // 0 or 64
    float acc[4][4] = {};
    for (int k0 = 0; k0 < D_DIM; k0 += 16) {
        { // load A tile 64x16 via float4
            int lr = t >> 2;
            int lk = (t & 3) * 4;
            int gr = row0 + lr;
            float4 v = make_float4(0.f, 0.f, 0.f, 0.f);
            if (gr < N) v = *(const float4*)(x + (size_t)gr * D_DIM + k0 + lk);
            As[lk + 0][lr] = v.x; As[lk + 1][lr] = v.y;
            As[lk + 2][lr] = v.z; As[lk + 3][lr] = v.w;
        }
        { // load B tile 16x64 via float4
            int lk = t >> 4;
            int lc = (t & 15) * 4;
            const float* wp = W + ((size_t)r * D_DIM + (k0 + lk)) * H_DIM + h0 + lc;
            *(float4*)&Bs[lk][lc] = *(const float4*)wp;
        }
        __syncthreads();
        #pragma unroll
        for (int kk = 0; kk < 16; ++kk) {
            float4 a4 = *(const float4*)&As[kk][ty * 4];
            float4 b4 = *(const float4*)&Bs[kk][tx * 4];
            acc[0][0] += a4.x * b4.x; acc[0][1] += a4.x * b4.y; acc[0][2] += a4.x * b4.z; acc[0][3] += a4.x * b4.w;
            acc[1][0] += a4.y * b4.x; acc[1][1] += a4.y * b4.y; acc[1][2] += a4.y * b4.z; acc[1][3] += a4.y * b4.w;
            acc[2][0] += a4.z * b4.x; acc[2][1] += a4.z * b4.y; acc[2][2] += a4.z * b4.z; acc[2][3] += a4.z * b4.w;
            acc[3][0] += a4.w * b4.x; acc[3][1] += a4.w * b4.y; acc[3][2] += a4.w * b4.z; acc[3][3] += a4.w * b4.w;
        }
        __syncthreads();
    }
    #pragma unroll
    for (int i = 0; i < 4; ++i) {
        int gr = row0 + ty * 4 + i;
        if (gr >= N) continue;
        size_t base = ((size_t)r * N + gr) * H_DIM + h0 + tx * 4;
        #pragma unroll
        for (int j = 0; j < 4; ++j) {
            float val = acc[i][j] + b[r * H_DIM + h0 + tx * 4 + j];
            Hout[base + j] = __float2bfloat16(val);
        }
    }
}

// ---------------- per-edge scores + per-row slot assignment
__global__ void kscore_kernel(const int* __restrict__ eidx, const int* __restrict__ etype,
                              const float* __restrict__ s1, const float* __restrict__ s2,
                              float* __restrict__ escore, int* __restrict__ slot,
                              int* __restrict__ cnt, int N, int E) {
    int e = blockIdx.x * blockDim.x + threadIdx.x;
    if (e >= E) return;
    int row = eidx[e];
    int col = eidx[E + e];
    int r = etype[e];
    float sc = s1[(size_t)r * N + row] + s2[(size_t)r * N + col];
    sc = (sc >= 0.f) ? sc : 0.2f * sc;
    escore[e] = sc;
    slot[e] = atomicAdd(&cnt[row], 1);
}

// ---------------- segment allocation (unordered, contiguous per row)
__global__ void kalloc_kernel(const int* __restrict__ cnt, int* __restrict__ ofs,
                              int* __restrict__ counter, int N) {
    int n = blockIdx.x * blockDim.x + threadIdx.x;
    if (n < N) ofs[n] = atomicAdd(counter, cnt[n]);
}

// ---------------- place perm-ordered edge records: packed offset + score
// poff = ((r*N+col) << 2) | r ; pscore = leaky score
__global__ void kplace2_kernel(const int* __restrict__ eidx, const int* __restrict__ etype,
                               const float* __restrict__ escore,
                               const int* __restrict__ ofs, const int* __restrict__ slot,
                               unsigned* __restrict__ poff, float* __restrict__ pscore,
                               int N, int E) {
    int e = blockIdx.x * blockDim.x + threadIdx.x;
    if (e >= E) return;
    int row = eidx[e];
    int col = eidx[E + e];
    int r = etype[e];
    int pos = ofs[row] + slot[e];
    poff[pos] = (((unsigned)(r * N + col)) << 2) | (unsigned)r;
    pscore[pos] = escore[e];
}

// ---------------- 4 rows per block (one wave each): in-register softmax + gather
__global__ void __launch_bounds__(256)
krow2_kernel(const unsigned* __restrict__ poff, const float* __restrict__ pscore,
             const int* __restrict__ ofs, const int* __restrict__ cnt,
             const __hip_bfloat16* __restrict__ Hall,
             float* __restrict__ out, int N) {
    const int wave = threadIdx.x >> 6;
    const int lane = threadIdx.x & 63;
    const int n = blockIdx.x * 4 + wave;
    if (n >= N) return;
    const int start = ofs[n];
    const int deg = cnt[n];

    float acc0 = 0.f, acc1 = 0.f;

    if (deg <= 64) {
        // ---- each lane owns one edge
        float sc = -1e30f;
        unsigned u = 0u;
        int r_i = 0;
        if (lane < deg) {
            u = poff[start + lane];
            sc = pscore[start + lane];
            r_i = (int)(u & 3u);
        }
        // per-relation max (all-lane butterfly), static-indexed
        float m0, m1, m2, m3;
        {
            float v0 = (r_i == 0 && lane < deg) ? sc : -1e30f;
            float v1 = (r_i == 1 && lane < deg) ? sc : -1e30f;
            float v2 = (r_i == 2 && lane < deg) ? sc : -1e30f;
            float v3 = (r_i == 3 && lane < deg) ? sc : -1e30f;
            #pragma unroll
            for (int o = 32; o > 0; o >>= 1) {
                v0 = fmaxf(v0, __shfl_xor(v0, o));
                v1 = fmaxf(v1, __shfl_xor(v1, o));
                v2 = fmaxf(v2, __shfl_xor(v2, o));
                v3 = fmaxf(v3, __shfl_xor(v3, o));
            }
            m0 = v0; m1 = v1; m2 = v2; m3 = v3;
        }
        float m_i = (r_i == 0) ? m0 : ((r_i == 1) ? m1 : ((r_i == 2) ? m2 : m3));
        float w = (lane < deg) ? __expf(sc - m_i) : 0.f;
        // per-relation sum
        float s0, s1, s2, s3;
        {
            float v0 = (r_i == 0) ? w : 0.f;
            float v1 = (r_i == 1) ? w : 0.f;
            float v2 = (r_i == 2) ? w : 0.f;
            float v3 = (r_i == 3) ? w : 0.f;
            #pragma unroll
            for (int o = 32; o > 0; o >>= 1) {
                v0 += __shfl_xor(v0, o);
                v1 += __shfl_xor(v1, o);
                v2 += __shfl_xor(v2, o);
                v3 += __shfl_xor(v3, o);
            }
            s0 = v0; s1 = v1; s2 = v2; s3 = v3;
        }
        float s_i = (r_i == 0) ? s0 : ((r_i == 1) ? s1 : ((r_i == 2) ? s2 : s3));
        float alpha = (lane < deg && s_i > 0.f) ? (w / s_i) : 0.f;

        // ---- pass 3: broadcast (alpha, off) lane by lane, 4 gathers in flight
        for (int j = 0; j < deg; j += 4) {
            #pragma unroll
            for (int jj = 0; jj < 4; ++jj) {
                int idx = j + jj;
                float al = __shfl(alpha, idx);
                int uj = __shfl((int)u, idx);
                if (idx < deg) {
                    const __hip_bfloat16* hp = Hall + (size_t)(((unsigned)uj) >> 2) * H_DIM;
                    acc0 += al * __bfloat162float(hp[lane]);
                    acc1 += al * __bfloat162float(hp[lane + 64]);
                }
            }
        }
    } else {
        // ---- rare fallback: deg > 64, memory-based 3 passes
        float v0 = -1e30f, v1 = -1e30f, v2 = -1e30f, v3 = -1e30f;
        for (int i = lane; i < deg; i += 64) {
            unsigned u = poff[start + i];
            float sc = pscore[start + i];
            int r = (int)(u & 3u);
            if (r == 0) v0 = fmaxf(v0, sc);
            else if (r == 1) v1 = fmaxf(v1, sc);
            else if (r == 2) v2 = fmaxf(v2, sc);
            else v3 = fmaxf(v3, sc);
        }
        #pragma unroll
        for (int o = 32; o > 0; o >>= 1) {
            v0 = fmaxf(v0, __shfl_xor(v0, o));
            v1 = fmaxf(v1, __shfl_xor(v1, o));
            v2 = fmaxf(v2, __shfl_xor(v2, o));
            v3 = fmaxf(v3, __shfl_xor(v3, o));
        }
        const float m0 = v0, m1 = v1, m2 = v2, m3 = v3;
        float t0 = 0.f, t1 = 0.f, t2 = 0.f, t3 = 0.f;
        for (int i = lane; i < deg; i += 64) {
            unsigned u = poff[start + i];
            float sc = pscore[start + i];
            int r = (int)(u & 3u);
            if (r == 0) t0 += __expf(sc - m0);
            else if (r == 1) t1 += __expf(sc - m1);
            else if (r == 2) t2 += __expf(sc - m2);
            else t3 += __expf(sc - m3);
        }
        #pragma unroll
        for (int o = 32; o > 0; o >>= 1) {
            t0 += __shfl_xor(t0, o);
            t1 += __shfl_xor(t1, o);
            t2 += __shfl_xor(t2, o);
            t3 += __shfl_xor(t3, o);
        }
        float i0 = (t0 > 0.f) ? 1.f / t0 : 0.f;
        float i1 = (t1 > 0.f) ? 1.f / t1 : 0.f;
        float i2 = (t2 > 0.f) ? 1.f / t2 : 0.f;
        float i3 = (t3 > 0.f) ? 1.f / t3 : 0.f;
        for (int i = 0; i < deg; ++i) {
            unsigned u = poff[start + i];     // wave-uniform broadcast load
            float sc = pscore[start + i];
            int r = (int)(u & 3u);
            float m_r = (r == 0) ? m0 : ((r == 1) ? m1 : ((r == 2) ? m2 : m3));
            float inv = (r == 0) ? i0 : ((r == 1) ? i1 : ((r == 2) ? i2 : i3));
            float al = __expf(sc - m_r) * inv;
            const __hip_bfloat16* hp = Hall + (size_t)(u >> 2) * H_DIM;
            acc0 += al * __bfloat162float(hp[lane]);
            acc1 += al * __bfloat162float(hp[lane + 64]);
        }
    }

    out[(size_t)n * H_DIM + lane] = acc0;
    out[(size_t)n * H_DIM + 64 + lane] = acc1;
}

// ---------------- launch
static inline char* carve(char*& p, size_t bytes) {
    char* q = p;
    p += (bytes + 255) & ~(size_t)255;
    return q;
}

extern "C" void kernel_launch(void* const* d_in, const int* in_sizes, int n_in,
                              void* d_out, int out_size, void* d_ws, size_t ws_size,
                              hipStream_t stream) {
    const float* x     = (const float*)d_in[0];
    const int*   eidx  = (const int*)d_in[1];
    const int*   etype = (const int*)d_in[2];
    const float* a     = (const float*)d_in[3];
    const float* W     = (const float*)d_in[4];
    const float* b     = (const float*)d_in[5];
    float* out = (float*)d_out;

    const int E = in_sizes[2];
    const int N = in_sizes[0] / D_DIM;

    char* p = (char*)d_ws;
    __hip_bfloat16* Hall = (__hip_bfloat16*)carve(p, (size_t)R_DIM * N * H_DIM * 2);
    float* s1     = (float*)carve(p, (size_t)R_DIM * N * 4);
    float* s2     = (float*)carve(p, (size_t)R_DIM * N * 4);
    float* v1     = (float*)carve(p, R_DIM * D_DIM * 4);
    float* v2     = (float*)carve(p, R_DIM * D_DIM * 4);
    float* c1     = (float*)carve(p, 64);
    float* c2     = (float*)carve(p, 64);
    float* escore = (float*)carve(p, (size_t)E * 4);
    int*   slot   = (int*)carve(p, (size_t)E * 4);
    unsigned* poff   = (unsigned*)carve(p, (size_t)E * 4);
    float*    pscore = (float*)carve(p, (size_t)E * 4);
    int*   ofs    = (int*)carve(p, (size_t)N * 4);
    int*   cnt    = (int*)carve(p, (size_t)N * 4 + 4);   // counter lives at cnt[N]
    int*   counter = cnt + N;

    // zero cnt + counter (contiguous)
    hipMemsetAsync(cnt, 0, (size_t)N * 4 + 4, stream);

    kv_kernel<<<4, 256, 0, stream>>>(W, b, a, v1, v2, c1, c2);
    ks_kernel<<<(N + 255) / 256, 256, 0, stream>>>(x, v1, v2, c1, c2, s1, s2, N);
    gemm_kernel<<<dim3(8, (N + 63) / 64), 256, 0, stream>>>(x, W, b, Hall, N);
    kscore_kernel<<<(E + 255) / 256, 256, 0, stream>>>(eidx, etype, s1, s2, escore, slot, cnt, N, E);
    kalloc_kernel<<<(N + 255) / 256, 256, 0, stream>>>(cnt, ofs, counter, N);
    kplace2_kernel<<<(E + 255) / 256, 256, 0, stream>>>(eidx, etype, escore, ofs, slot, poff, pscore, N, E);
    krow2_kernel<<<(N + 3) / 4, 256, 0, stream>>>(poff, pscore, ofs, cnt, Hall, out, N);
}

// Round 3
// 232.282 us; speedup vs baseline: 2.3753x; 1.4537x over previous
//
#include <hip/hip_runtime.h>
#include <hip/hip_bf16.h>

#define D_DIM 256
#define H_DIM 128
#define R_DIM 4

typedef __bf16 bf16x8 __attribute__((ext_vector_type(8)));
typedef float f32x4 __attribute__((ext_vector_type(4)));

__device__ __forceinline__ unsigned short f2bf(float f) {
    union { float f; unsigned u; } v; v.f = f;
    unsigned r = (v.u + 0x7FFFu + ((v.u >> 16) & 1u)) >> 16;   // RNE
    return (unsigned short)r;
}

// ---------------- x (N,256) fp32 -> bf16
__global__ void xcvt_kernel(const float* __restrict__ x, unsigned short* __restrict__ xb, int total8) {
    int i = blockIdx.x * blockDim.x + threadIdx.x;
    int stride = gridDim.x * blockDim.x;
    for (; i < total8; i += stride) {
        const float4* xp = (const float4*)(x + (size_t)i * 8);
        float4 v0 = xp[0], v1 = xp[1];
        uint4 o;
        o.x = (unsigned)f2bf(v0.x) | ((unsigned)f2bf(v0.y) << 16);
        o.y = (unsigned)f2bf(v0.z) | ((unsigned)f2bf(v0.w) << 16);
        o.z = (unsigned)f2bf(v1.x) | ((unsigned)f2bf(v1.y) << 16);
        o.w = (unsigned)f2bf(v1.z) | ((unsigned)f2bf(v1.w) << 16);
        *(uint4*)(xb + (size_t)i * 8) = o;
    }
}

// ---------------- W (R,256,128) fp32 -> Wt (R,128,256) bf16 (transposed, K-contiguous)
__global__ void wtcvt_kernel(const float* __restrict__ W, unsigned short* __restrict__ Wt) {
    int idx = blockIdx.x * blockDim.x + threadIdx.x;
    if (idx >= R_DIM * D_DIM * H_DIM) return;
    int d = idx & 255;
    int h = (idx >> 8) & 127;
    int r = idx >> 15;
    Wt[idx] = f2bf(W[((size_t)(r * D_DIM + d)) * H_DIM + h]);
}

// ---------------- K_v: v1[r][d] = sum_h W[r][d][h]*a1[h]; v2 with a2; c1[r]=b[r].a1, c2[r]=b[r].a2
__global__ void kv_kernel(const float* __restrict__ W, const float* __restrict__ b,
                          const float* __restrict__ a,
                          float* __restrict__ v1, float* __restrict__ v2,
                          float* __restrict__ c1, float* __restrict__ c2) {
    int t = blockIdx.x * blockDim.x + threadIdx.x;
    if (t < R_DIM * D_DIM) {
        int r = t >> 8;
        int d = t & 255;
        const float* wp = W + ((size_t)r * D_DIM + d) * H_DIM;
        float acc1 = 0.f, acc2 = 0.f;
        for (int h = 0; h < H_DIM; ++h) {
            float w = wp[h];
            acc1 += w * a[h];
            acc2 += w * a[H_DIM + h];
        }
        v1[t] = acc1; v2[t] = acc2;
    }
    if (t < R_DIM) {
        const float* bp = b + t * H_DIM;
        float acc1 = 0.f, acc2 = 0.f;
        for (int h = 0; h < H_DIM; ++h) {
            acc1 += bp[h] * a[h];
            acc2 += bp[h] * a[H_DIM + h];
        }
        c1[t] = acc1; c2[t] = acc2;
    }
}

// ---------------- K_s: s1[r*N+n] = x[n].v1[r] + c1[r]; s2 likewise (exact fp32 path)
__global__ void ks_kernel(const float* __restrict__ x,
                          const float* __restrict__ v1, const float* __restrict__ v2,
                          const float* __restrict__ c1, const float* __restrict__ c2,
                          float* __restrict__ s1, float* __restrict__ s2, int N) {
    __shared__ float sv1[R_DIM * D_DIM];
    __shared__ float sv2[R_DIM * D_DIM];
    for (int i = threadIdx.x; i < R_DIM * D_DIM; i += blockDim.x) {
        sv1[i] = v1[i]; sv2[i] = v2[i];
    }
    __syncthreads();
    int n = blockIdx.x * blockDim.x + threadIdx.x;
    if (n >= N) return;
    float a1[R_DIM] = {0.f, 0.f, 0.f, 0.f};
    float a2[R_DIM] = {0.f, 0.f, 0.f, 0.f};
    const float4* xp = (const float4*)(x + (size_t)n * D_DIM);
    for (int d4 = 0; d4 < D_DIM / 4; ++d4) {
        float4 xv = xp[d4];
        #pragma unroll
        for (int r = 0; r < R_DIM; ++r) {
            float4 w1 = *(const float4*)&sv1[r * D_DIM + d4 * 4];
            float4 w2 = *(const float4*)&sv2[r * D_DIM + d4 * 4];
            a1[r] += xv.x * w1.x + xv.y * w1.y + xv.z * w1.z + xv.w * w1.w;
            a2[r] += xv.x * w2.x + xv.y * w2.y + xv.z * w2.z + xv.w * w2.w;
        }
    }
    #pragma unroll
    for (int r = 0; r < R_DIM; ++r) {
        s1[(size_t)r * N + n] = a1[r] + c1[r];
        s2[(size_t)r * N + n] = a2[r] + c2[r];
    }
}

// ---------------- MFMA GEMM: Hall[r][n][h] = bf16( xb[n,:] . Wt[r][h,:] + b[r][h] )
// BM=128, BN=128 (one relation), BK=64, 256 threads = 4 waves (2x2), wave tile 64x64.
#define LDS_STRIDE 144   // bytes per row (64 bf16 = 128B + 16B pad): bank stride 36 words -> 2-way max
__global__ void __launch_bounds__(256)
gemm_mfma_kernel(const unsigned short* __restrict__ xb, const unsigned short* __restrict__ Wt,
                 const float* __restrict__ b, __hip_bfloat16* __restrict__ Hall, int N) {
    __shared__ __align__(16) char Alds[128 * LDS_STRIDE];
    __shared__ __align__(16) char Blds[128 * LDS_STRIDE];

    const int t = threadIdx.x;
    const int lane = t & 63;
    const int w = t >> 6;
    const int wm = w >> 1, wn = w & 1;
    const int row0 = blockIdx.x * 128;
    const int r = blockIdx.y;

    f32x4 acc[4][4];
    #pragma unroll
    for (int i = 0; i < 4; ++i)
        #pragma unroll
        for (int j = 0; j < 4; ++j)
            acc[i][j] = (f32x4){0.f, 0.f, 0.f, 0.f};

    // per-lane fragment base offsets (bytes)
    const int l15 = lane & 15;
    const int kOfs = (lane >> 4) * 16;          // (lane>>4)*8 bf16
    const int aBase = (wm * 64 + l15) * LDS_STRIDE + kOfs;
    const int bBase = (wn * 64 + l15) * LDS_STRIDE + kOfs;

    for (int k0 = 0; k0 < D_DIM; k0 += 64) {
        // ---- stage A (128x64) and B (128x64) via regs, padded LDS rows
        #pragma unroll
        for (int pass = 0; pass < 4; ++pass) {
            int idx = t + pass * 256;
            int row = idx >> 3;
            int ch = idx & 7;
            int gr = row0 + row; if (gr > N - 1) gr = N - 1;
            uint4 va = *(const uint4*)(xb + (size_t)gr * D_DIM + k0 + ch * 8);
            uint4 vb = *(const uint4*)(Wt + ((size_t)(r * H_DIM + row)) * D_DIM + k0 + ch * 8);
            *(uint4*)(Alds + row * LDS_STRIDE + ch * 16) = va;
            *(uint4*)(Blds + row * LDS_STRIDE + ch * 16) = vb;
        }
        __syncthreads();

        #pragma unroll
        for (int kk = 0; kk < 2; ++kk) {          // two K=32 sub-steps
            const int kb = kk * 64;               // 32 bf16 = 64 bytes
            bf16x8 af[4], bf[4];
            #pragma unroll
            for (int mf = 0; mf < 4; ++mf)
                af[mf] = *(const bf16x8*)(Alds + aBase + mf * 16 * LDS_STRIDE + kb);
            #pragma unroll
            for (int nf = 0; nf < 4; ++nf)
                bf[nf] = *(const bf16x8*)(Blds + bBase + nf * 16 * LDS_STRIDE + kb);
            #pragma unroll
            for (int mf = 0; mf < 4; ++mf)
                #pragma unroll
                for (int nf = 0; nf < 4; ++nf)
                    acc[mf][nf] = __builtin_amdgcn_mfma_f32_16x16x32_bf16(
                        af[mf], bf[nf], acc[mf][nf], 0, 0, 0);
        }
        __syncthreads();
    }

    // ---- epilogue: C/D layout col=lane&15, row=(lane>>4)*4+j
    #pragma unroll
    for (int nf = 0; nf < 4; ++nf) {
        int col = wn * 64 + nf * 16 + l15;
        float bias = b[r * H_DIM + col];
        #pragma unroll
        for (int mf = 0; mf < 4; ++mf) {
            int rowb = row0 + wm * 64 + mf * 16 + (lane >> 4) * 4;
            #pragma unroll
            for (int j = 0; j < 4; ++j) {
                int gr = rowb + j;
                if (gr < N) {
                    float val = acc[mf][nf][j] + bias;
                    Hall[((size_t)r * N + gr) * H_DIM + col] = __float2bfloat16(val);
                }
            }
        }
    }
}

// ---------------- per-edge scores + per-row slot assignment
__global__ void kscore_kernel(const int* __restrict__ eidx, const int* __restrict__ etype,
                              const float* __restrict__ s1, const float* __restrict__ s2,
                              float* __restrict__ escore, int* __restrict__ slot,
                              int* __restrict__ cnt, int N, int E) {
    int e = blockIdx.x * blockDim.x + threadIdx.x;
    if (e >= E) return;
    int row = eidx[e];
    int col = eidx[E + e];
    int r = etype[e];
    float sc = s1[(size_t)r * N + row] + s2[(size_t)r * N + col];
    sc = (sc >= 0.f) ? sc : 0.2f * sc;
    escore[e] = sc;
    slot[e] = atomicAdd(&cnt[row], 1);
}

// ---------------- segment allocation (unordered, contiguous per row)
__global__ void kalloc_kernel(const int* __restrict__ cnt, int* __restrict__ ofs,
                              int* __restrict__ counter, int N) {
    int n = blockIdx.x * blockDim.x + threadIdx.x;
    if (n < N) ofs[n] = atomicAdd(counter, cnt[n]);
}

// ---------------- place perm-ordered edge records: packed offset + score
__global__ void kplace2_kernel(const int* __restrict__ eidx, const int* __restrict__ etype,
                               const float* __restrict__ escore,
                               const int* __restrict__ ofs, const int* __restrict__ slot,
                               unsigned* __restrict__ poff, float* __restrict__ pscore,
                               int N, int E) {
    int e = blockIdx.x * blockDim.x + threadIdx.x;
    if (e >= E) return;
    int row = eidx[e];
    int col = eidx[E + e];
    int r = etype[e];
    int pos = ofs[row] + slot[e];
    poff[pos] = (((unsigned)(r * N + col)) << 2) | (unsigned)r;
    pscore[pos] = escore[e];
}

// ---------------- 4 rows per block (one wave each): in-register softmax + gather
__global__ void __launch_bounds__(256)
krow2_kernel(const unsigned* __restrict__ poff, const float* __restrict__ pscore,
             const int* __restrict__ ofs, const int* __restrict__ cnt,
             const __hip_bfloat16* __restrict__ Hall,
             float* __restrict__ out, int N) {
    const int wave = threadIdx.x >> 6;
    const int lane = threadIdx.x & 63;
    const int n = blockIdx.x * 4 + wave;
    if (n >= N) return;
    const int start = ofs[n];
    const int deg = cnt[n];

    float acc0 = 0.f, acc1 = 0.f;

    if (deg <= 64) {
        float sc = -1e30f;
        unsigned u = 0u;
        int r_i = 0;
        if (lane < deg) {
            u = poff[start + lane];
            sc = pscore[start + lane];
            r_i = (int)(u & 3u);
        }
        float m0, m1, m2, m3;
        {
            float v0 = (r_i == 0 && lane < deg) ? sc : -1e30f;
            float v1 = (r_i == 1 && lane < deg) ? sc : -1e30f;
            float v2 = (r_i == 2 && lane < deg) ? sc : -1e30f;
            float v3 = (r_i == 3 && lane < deg) ? sc : -1e30f;
            #pragma unroll
            for (int o = 32; o > 0; o >>= 1) {
                v0 = fmaxf(v0, __shfl_xor(v0, o));
                v1 = fmaxf(v1, __shfl_xor(v1, o));
                v2 = fmaxf(v2, __shfl_xor(v2, o));
                v3 = fmaxf(v3, __shfl_xor(v3, o));
            }
            m0 = v0; m1 = v1; m2 = v2; m3 = v3;
        }
        float m_i = (r_i == 0) ? m0 : ((r_i == 1) ? m1 : ((r_i == 2) ? m2 : m3));
        float wgt = (lane < deg) ? __expf(sc - m_i) : 0.f;
        float s0, s1, s2, s3;
        {
            float v0 = (r_i == 0) ? wgt : 0.f;
            float v1 = (r_i == 1) ? wgt : 0.f;
            float v2 = (r_i == 2) ? wgt : 0.f;
            float v3 = (r_i == 3) ? wgt : 0.f;
            #pragma unroll
            for (int o = 32; o > 0; o >>= 1) {
                v0 += __shfl_xor(v0, o);
                v1 += __shfl_xor(v1, o);
                v2 += __shfl_xor(v2, o);
                v3 += __shfl_xor(v3, o);
            }
            s0 = v0; s1 = v1; s2 = v2; s3 = v3;
        }
        float s_i = (r_i == 0) ? s0 : ((r_i == 1) ? s1 : ((r_i == 2) ? s2 : s3));
        float alpha = (lane < deg && s_i > 0.f) ? (wgt / s_i) : 0.f;

        for (int j = 0; j < deg; j += 4) {
            #pragma unroll
            for (int jj = 0; jj < 4; ++jj) {
                int idx = j + jj;
                float al = __shfl(alpha, idx);
                int uj = __shfl((int)u, idx);
                if (idx < deg) {
                    const __hip_bfloat16* hp = Hall + (size_t)(((unsigned)uj) >> 2) * H_DIM;
                    acc0 += al * __bfloat162float(hp[lane]);
                    acc1 += al * __bfloat162float(hp[lane + 64]);
                }
            }
        }
    } else {
        float v0 = -1e30f, v1 = -1e30f, v2 = -1e30f, v3 = -1e30f;
        for (int i = lane; i < deg; i += 64) {
            unsigned u = poff[start + i];
            float sc = pscore[start + i];
            int r = (int)(u & 3u);
            if (r == 0) v0 = fmaxf(v0, sc);
            else if (r == 1) v1 = fmaxf(v1, sc);
            else if (r == 2) v2 = fmaxf(v2, sc);
            else v3 = fmaxf(v3, sc);
        }
        #pragma unroll
        for (int o = 32; o > 0; o >>= 1) {
            v0 = fmaxf(v0, __shfl_xor(v0, o));
            v1 = fmaxf(v1, __shfl_xor(v1, o));
            v2 = fmaxf(v2, __shfl_xor(v2, o));
            v3 = fmaxf(v3, __shfl_xor(v3, o));
        }
        const float m0 = v0, m1 = v1, m2 = v2, m3 = v3;
        float t0 = 0.f, t1 = 0.f, t2 = 0.f, t3 = 0.f;
        for (int i = lane; i < deg; i += 64) {
            unsigned u = poff[start + i];
            float sc = pscore[start + i];
            int r = (int)(u & 3u);
            if (r == 0) t0 += __expf(sc - m0);
            else if (r == 1) t1 += __expf(sc - m1);
            else if (r == 2) t2 += __expf(sc - m2);
            else t3 += __expf(sc - m3);
        }
        #pragma unroll
        for (int o = 32; o > 0; o >>= 1) {
            t0 += __shfl_xor(t0, o);
            t1 += __shfl_xor(t1, o);
            t2 += __shfl_xor(t2, o);
            t3 += __shfl_xor(t3, o);
        }
        float i0 = (t0 > 0.f) ? 1.f / t0 : 0.f;
        float i1 = (t1 > 0.f) ? 1.f / t1 : 0.f;
        float i2 = (t2 > 0.f) ? 1.f / t2 : 0.f;
        float i3 = (t3 > 0.f) ? 1.f / t3 : 0.f;
        for (int i = 0; i < deg; ++i) {
            unsigned u = poff[start + i];
            float sc = pscore[start + i];
            int r = (int)(u & 3u);
            float m_r = (r == 0) ? m0 : ((r == 1) ? m1 : ((r == 2) ? m2 : m3));
            float inv = (r == 0) ? i0 : ((r == 1) ? i1 : ((r == 2) ? i2 : i3));
            float al = __expf(sc - m_r) * inv;
            const __hip_bfloat16* hp = Hall + (size_t)(u >> 2) * H_DIM;
            acc0 += al * __bfloat162float(hp[lane]);
            acc1 += al * __bfloat162float(hp[lane + 64]);
        }
    }

    out[(size_t)n * H_DIM + lane] = acc0;
    out[(size_t)n * H_DIM + 64 + lane] = acc1;
}

// ---------------- launch
static inline char* carve(char*& p, size_t bytes) {
    char* q = p;
    p += (bytes + 255) & ~(size_t)255;
    return q;
}

extern "C" void kernel_launch(void* const* d_in, const int* in_sizes, int n_in,
                              void* d_out, int out_size, void* d_ws, size_t ws_size,
                              hipStream_t stream) {
    const float* x     = (const float*)d_in[0];
    const int*   eidx  = (const int*)d_in[1];
    const int*   etype = (const int*)d_in[2];
    const float* a     = (const float*)d_in[3];
    const float* W     = (const float*)d_in[4];
    const float* b     = (const float*)d_in[5];
    float* out = (float*)d_out;

    const int E = in_sizes[2];
    const int N = in_sizes[0] / D_DIM;

    char* p = (char*)d_ws;
    __hip_bfloat16* Hall = (__hip_bfloat16*)carve(p, (size_t)R_DIM * N * H_DIM * 2);
    unsigned short* xb   = (unsigned short*)carve(p, (size_t)N * D_DIM * 2);
    unsigned short* Wt   = (unsigned short*)carve(p, (size_t)R_DIM * D_DIM * H_DIM * 2);
    float* s1     = (float*)carve(p, (size_t)R_DIM * N * 4);
    float* s2     = (float*)carve(p, (size_t)R_DIM * N * 4);
    float* v1     = (float*)carve(p, R_DIM * D_DIM * 4);
    float* v2     = (float*)carve(p, R_DIM * D_DIM * 4);
    float* c1     = (float*)carve(p, 64);
    float* c2     = (float*)carve(p, 64);
    float* escore = (float*)carve(p, (size_t)E * 4);
    int*   slot   = (int*)carve(p, (size_t)E * 4);
    unsigned* poff   = (unsigned*)carve(p, (size_t)E * 4);
    float*    pscore = (float*)carve(p, (size_t)E * 4);
    int*   ofs    = (int*)carve(p, (size_t)N * 4);
    int*   cnt    = (int*)carve(p, (size_t)N * 4 + 4);   // counter lives at cnt[N]
    int*   counter = cnt + N;

    hipMemsetAsync(cnt, 0, (size_t)N * 4 + 4, stream);

    kv_kernel<<<4, 256, 0, stream>>>(W, b, a, v1, v2, c1, c2);
    ks_kernel<<<(N + 255) / 256, 256, 0, stream>>>(x, v1, v2, c1, c2, s1, s2, N);
    xcvt_kernel<<<2048, 256, 0, stream>>>(x, xb, N * D_DIM / 8);
    wtcvt_kernel<<<(R_DIM * D_DIM * H_DIM + 255) / 256, 256, 0, stream>>>(W, Wt);
    gemm_mfma_kernel<<<dim3((N + 127) / 128, R_DIM), 256, 0, stream>>>(xb, Wt, b, Hall, N);
    kscore_kernel<<<(E + 255) / 256, 256, 0, stream>>>(eidx, etype, s1, s2, escore, slot, cnt, N, E);
    kalloc_kernel<<<(N + 255) / 256, 256, 0, stream>>>(cnt, ofs, counter, N);
    kplace2_kernel<<<(E + 255) / 256, 256, 0, stream>>>(eidx, etype, escore, ofs, slot, poff, pscore, N, E);
    krow2_kernel<<<(N + 3) / 4, 256, 0, stream>>>(poff, pscore, ofs, cnt, Hall, out, N);
}